// Round 21
// baseline (334.280 us; speedup 1.0000x reference)
//
#include <hip/hip_runtime.h>
#include <hip/hip_bf16.h>

#define NN 10000
#define NP 10240  // GH rows padded: 32 m-chunks x 20 m-groups x 16 rows
#define NE 50000
#define FIN 40
#define FE 10
#define MCH 20    // m-groups per contract m-chunk
// L = 64

typedef float f32x4 __attribute__((ext_vector_type(4)));
typedef short s16x8 __attribute__((ext_vector_type(8)));

__device__ __forceinline__ float bcast(float v, int lane) {
    return __uint_as_float(__builtin_amdgcn_readlane(__float_as_uint(v), lane));
}
__device__ __forceinline__ int bcast_i(int v, int lane) {
    return __builtin_amdgcn_readlane(v, lane);
}
__device__ __forceinline__ ushort f2bf(float f) {
    uint u = __float_as_uint(f);
    uint r = (u + 0x7FFFu + ((u >> 16) & 1u)) >> 16;
    return (ushort)r;
}
__device__ __forceinline__ float bf2f(ushort h) {
    return __uint_as_float(((uint)h) << 16);
}

// ---------------- CSR build ----------------
__global__ void k_count(const int* __restrict__ ei, int* __restrict__ deg) {
    int e = blockIdx.x * 256 + threadIdx.x;
    if (e < NE) atomicAdd(&deg[ei[NE + e]], 1);
}

__global__ __launch_bounds__(1024) void k_scan(const int* __restrict__ deg,
                                               int* __restrict__ rowp,
                                               int* __restrict__ fill,
                                               float* __restrict__ invd) {
    __shared__ int wsum[16];
    __shared__ int chunkbase;
    int tid = threadIdx.x, lane = tid & 63, wv = tid >> 6;
    if (tid == 0) chunkbase = 0;
    __syncthreads();
    for (int base = 0; base < NN; base += 1024) {
        int idx = base + tid;
        int v = (idx < NN) ? deg[idx] : 0;
        int s = v;
#pragma unroll
        for (int off = 1; off < 64; off <<= 1) {
            int t = __shfl_up(s, off, 64);
            if (lane >= off) s += t;
        }
        if (lane == 63) wsum[wv] = s;
        __syncthreads();
        int carry = chunkbase;
        if (wv == 0 && lane < 16) {
            int x = wsum[lane];
#pragma unroll
            for (int off = 1; off < 16; off <<= 1) {
                int t = __shfl_up(x, off, 64);
                if (lane >= off) x += t;
            }
            wsum[lane] = x;  // inclusive over waves
        }
        __syncthreads();
        int wpre = (wv == 0) ? 0 : wsum[wv - 1];
        int incl = carry + wpre + s;
        if (idx < NN) {
            rowp[idx] = incl - v;
            fill[idx] = incl - v;
            invd[idx] = 1.0f / (float)(v > 0 ? v : 1);
        }
        __syncthreads();
        if (tid == 0) chunkbase = carry + wsum[15];
        __syncthreads();
    }
    if (tid == 0) rowp[NN] = NE;
}

__global__ void k_fill(const int* __restrict__ ei, int* __restrict__ fill,
                       int* __restrict__ csrs, int* __restrict__ csre) {
    int e = blockIdx.x * 256 + threadIdx.x;
    if (e < NE) {
        int d = ei[NE + e];
        int p = atomicAdd(&fill[d], 1);
        csrs[p] = ei[e];
        csre[p] = e;
    }
}

// ---------------- W2 split-bf16, transposed to [o][ki] (ki = k*64+i) ----------------
__global__ __launch_bounds__(256) void k_w2f(const float* __restrict__ n2w,
                                             ushort* __restrict__ W2FH,
                                             ushort* __restrict__ W2FL) {
    int lane = threadIdx.x & 63, wvl = threadIdx.x >> 6;
    int ki = blockIdx.x * 4 + wvl;
    float v = n2w[(size_t)ki * 64 + lane];
    ushort hi = f2bf(v);
    ushort lo = f2bf(v - bf2f(hi));
    W2FH[(size_t)lane * 4096 + ki] = hi;
    W2FL[(size_t)lane * 4096 + ki] = lo;
}

// ---------------- edge MLP: hE = relu(edge_attr @ nn1_w + nn1_b) ----------------
__global__ __launch_bounds__(256) void k_edge_h(const float* __restrict__ ea,
                                                const float* __restrict__ w1,
                                                const float* __restrict__ b1,
                                                float* __restrict__ hE) {
    int lane = threadIdx.x & 63, wv = threadIdx.x >> 6;
    int e = blockIdx.x * 4 + wv;
    float av = (lane < FE) ? ea[e * FE + lane] : 0.f;
    float acc = b1[lane];
#pragma unroll
    for (int j = 0; j < FE; ++j) acc += bcast(av, j) * w1[j * 64 + lane];
    hE[e * 64 + lane] = fmaxf(acc, 0.f);
}

// ---------------- lin0 ----------------
__global__ __launch_bounds__(256) void k_lin0(const float* __restrict__ x,
                                              const float* __restrict__ w0,
                                              const float* __restrict__ b0,
                                              float* __restrict__ F) {
    int lane = threadIdx.x & 63, wv = threadIdx.x >> 6;
    int n = blockIdx.x * 4 + wv;
    float xv = (lane < FIN) ? x[n * FIN + lane] : 0.f;
    float acc = b0[lane];
#pragma unroll
    for (int k = 0; k < FIN; ++k) acc += bcast(xv, k) * w0[k * 64 + lane];
    F[n * 64 + lane] = fmaxf(acc, 0.f);
}

// ---------------- gather: GH[n][ki] flat layout, CONTIGUOUS 1KB stores ----------
// R20 diagnosis: R15's tiled GHT made gather stores 16B-at-256B-stride
// (quarter-line, 2.4 TB/s); plain [n][ki] was already full-line for the
// contract A-reads (lanes agrp0-3 fill each 64B line), so revert. The Gs
// row IS the output layout: stores are straight contiguous copies.
// Two-pass 16KB LDS (8 blocks/CU cap) + 2-edge unroll kept from R19.
__global__ __launch_bounds__(256) void k_gather(
    const float* __restrict__ F, const float* __restrict__ hE,
    const int* __restrict__ rowp, const int* __restrict__ csrs,
    const int* __restrict__ csre,
    ushort* __restrict__ GH, float* __restrict__ Usb) {
    __shared__ __align__(16) ushort Gs[4][2048];  // 16 KB
    int tid = threadIdx.x, lane = tid & 63, wv = tid >> 6;
    int n = __builtin_amdgcn_readfirstlane(blockIdx.x * 4 + wv);
    int beg = __builtin_amdgcn_readfirstlane(rowp[n]);
    int end = __builtin_amdgcn_readfirstlane(rowp[n + 1]);

    float G[64];
#pragma unroll
    for (int k = 0; k < 64; ++k) G[k] = 0.f;
    float usum = 0.f;
    {
        int p0 = beg + lane;
        int sl = (p0 < end) ? csrs[p0] : 0;
        int el = (p0 < end) ? csre[p0] : 0;
        int nb = min(end - beg, 64);
        int j = 0;
        for (; j + 1 < nb; j += 2) {
            int s0 = bcast_i(sl, j), e0 = bcast_i(el, j);
            int s1 = bcast_i(sl, j + 1), e1 = bcast_i(el, j + 1);
            float u0 = F[(size_t)s0 * 64 + lane];
            float h0 = hE[(size_t)e0 * 64 + lane];
            float u1 = F[(size_t)s1 * 64 + lane];
            float h1 = hE[(size_t)e1 * 64 + lane];
            usum += u0;
            usum += u1;
#pragma unroll
            for (int k = 0; k < 64; ++k)
                G[k] = fmaf(bcast(h1, k), u1, fmaf(bcast(h0, k), u0, G[k]));
        }
        if (j < nb) {
            int s0 = bcast_i(sl, j), e0 = bcast_i(el, j);
            float u0 = F[(size_t)s0 * 64 + lane];
            float h0 = hE[(size_t)e0 * 64 + lane];
            usum += u0;
#pragma unroll
            for (int k = 0; k < 64; ++k) G[k] = fmaf(bcast(h0, k), u0, G[k]);
        }
        for (int p = beg + 64; p < end; ++p) {  // deg>64: rare
            int s = __builtin_amdgcn_readfirstlane(csrs[p]);
            int e = __builtin_amdgcn_readfirstlane(csre[p]);
            float u = F[(size_t)s * 64 + lane];
            float hv = hE[(size_t)e * 64 + lane];
            usum += u;
#pragma unroll
            for (int k = 0; k < 64; ++k) G[k] = fmaf(bcast(hv, k), u, G[k]);
        }
    }
    Usb[(size_t)n * 64 + lane] = usum;
    ushort* gout = GH + (size_t)n * 4096;
    // pass 0: ki in [0,2048)
#pragma unroll
    for (int k = 0; k < 32; ++k) Gs[wv][k * 64 + lane] = f2bf(G[k]);
    __syncthreads();
#pragma unroll
    for (int it = 0; it < 4; ++it) {
        int idx = it * 512 + lane * 8;
        *(s16x8*)&gout[idx] = *(const s16x8*)&Gs[wv][idx];
    }
    __syncthreads();
    // pass 1: ki in [2048,4096)
#pragma unroll
    for (int k = 0; k < 32; ++k) Gs[wv][k * 64 + lane] = f2bf(G[32 + k]);
    __syncthreads();
#pragma unroll
    for (int it = 0; it < 4; ++it) {
        int idx = it * 512 + lane * 8;
        *(s16x8*)&gout[2048 + idx] = *(const s16x8*)&Gs[wv][idx];
    }
}

// ---------------- contract: B-stationary, GH[n][ki] A reads (full-line) ----------------
// Grid 512 = 32 mc x 16 ks (2 blocks/CU, BH+BL in LDS). Per A-load instr:
// 16 node-rows x 64B fully-used lines (agrp 0..3 cover each line).
// 8 waves = 4 o-tiles x 2 m-halves; 2 m-groups x hi/lo-split accs = 4 chains.
__global__ __launch_bounds__(512) void k_contract(
    const ushort* __restrict__ GH, const ushort* __restrict__ W2FH,
    const ushort* __restrict__ W2FL, float* __restrict__ AggP) {
    __shared__ __align__(16) ushort BH[64 * 264];  // 33792 B
    __shared__ __align__(16) ushort BL[64 * 264];  // 33792 B
    int tid = threadIdx.x, lane = tid & 63, wv = tid >> 6;
    int ks = blockIdx.x & 15;  // ki sixteenth
    int mc = blockIdx.x >> 4;  // 0..31
    int kbase = ks * 256;
    int otile = wv & 3, mhalf = wv >> 2;
    int arow = lane & 15, agrp = lane >> 4;
    int o = otile * 16 + arow;

#pragma unroll
    for (int rep = 0; rep < 4; ++rep) {
        int off = rep * 4096 + tid * 8;
        int row = off >> 8, col = off & 255;
        *(s16x8*)&BH[row * 264 + col] =
            *(const s16x8*)&W2FH[(size_t)row * 4096 + kbase + col];
        *(s16x8*)&BL[row * 264 + col] =
            *(const s16x8*)&W2FL[(size_t)row * 4096 + kbase + col];
    }
    __syncthreads();

    int mg0 = mc * MCH;
    int mgend = mg0 + MCH;
    float* ap = AggP + (size_t)ks * NN * 64;
    for (int mg = mg0 + mhalf * 2; mg < mgend; mg += 4) {
        const ushort* pA = GH + (size_t)(mg * 16 + arow) * 4096 + kbase;
        const ushort* pB = pA + 65536;  // (mg+1)*16 rows later, same arow
        f32x4 a0h = {0.f, 0.f, 0.f, 0.f};
        f32x4 a0l = {0.f, 0.f, 0.f, 0.f};
        f32x4 a1h = {0.f, 0.f, 0.f, 0.f};
        f32x4 a1l = {0.f, 0.f, 0.f, 0.f};
#pragma unroll 4
        for (int s = 0; s < 8; ++s) {
            int kil = s * 32 + agrp * 8;
            s16x8 a0 = *(const s16x8*)&pA[kil];
            s16x8 a1 = *(const s16x8*)&pB[kil];
            s16x8 bh = *(const s16x8*)&BH[o * 264 + kil];
            s16x8 bl = *(const s16x8*)&BL[o * 264 + kil];
            a0h = __builtin_amdgcn_mfma_f32_16x16x32_bf16(a0, bh, a0h, 0, 0, 0);
            a1h = __builtin_amdgcn_mfma_f32_16x16x32_bf16(a1, bh, a1h, 0, 0, 0);
            a0l = __builtin_amdgcn_mfma_f32_16x16x32_bf16(a0, bl, a0l, 0, 0, 0);
            a1l = __builtin_amdgcn_mfma_f32_16x16x32_bf16(a1, bl, a1l, 0, 0, 0);
        }
        f32x4 acc0 = a0h + a0l;
        f32x4 acc1 = a1h + a1l;
#pragma unroll
        for (int r = 0; r < 4; ++r) {
            int n0r = mg * 16 + agrp * 4 + r;
            if (n0r < NN) ap[(size_t)n0r * 64 + o] = acc0[r];
            int n1r = (mg + 1) * 16 + agrp * 4 + r;
            if (n1r < NN) ap[(size_t)n1r * 64 + o] = acc1[r];
        }
    }
}

// ---------------- epilogue (R15 verbatim) ----------------
__global__ __launch_bounds__(256) void k_epi(
    const float* __restrict__ AggP, const float* __restrict__ Usb,
    const float* __restrict__ B2, const float* __restrict__ invd,
    const float* __restrict__ F, const float* __restrict__ Wroot,
    const float* __restrict__ broot, const float* __restrict__ Wih,
    const float* __restrict__ Whh, const float* __restrict__ bih,
    const float* __restrict__ bhh, float* __restrict__ Fout) {
    int lane = threadIdx.x & 63, wv = threadIdx.x >> 6;
    int nq = blockIdx.x * 16 + wv * 4;

    float fv[4], uv[4], aa[4], rt[4], bt[4];
#pragma unroll
    for (int q = 0; q < 4; ++q) {
        size_t idx = (size_t)(nq + q) * 64 + lane;
        fv[q] = F[idx];
        uv[q] = Usb[idx];
        float s = 0.f;
#pragma unroll
        for (int ks = 0; ks < 16; ++ks) s += AggP[(size_t)ks * NN * 64 + idx];
        aa[q] = s;
        rt[q] = broot[lane];
        bt[q] = 0.f;
    }
#pragma unroll 8
    for (int k = 0; k < 64; ++k) {
        float wr = Wroot[k * 64 + lane];
        float b2 = B2[k * 64 + lane];
#pragma unroll
        for (int q = 0; q < 4; ++q) {
            rt[q] = fmaf(bcast(fv[q], k), wr, rt[q]);
            bt[q] = fmaf(bcast(uv[q], k), b2, bt[q]);
        }
    }
    float m[4];
#pragma unroll
    for (int q = 0; q < 4; ++q)
        m[q] = fmaxf((aa[q] + bt[q]) * invd[nq + q] + rt[q], 0.f);

    float sr[4], sz[4], gn[4], gh[4];
#pragma unroll
    for (int q = 0; q < 4; ++q) {
        sr[q] = bih[lane] + bhh[lane];
        sz[q] = bih[64 + lane] + bhh[64 + lane];
        gn[q] = bih[128 + lane];
        gh[q] = bhh[128 + lane];
    }
#pragma unroll 8
    for (int k = 0; k < 64; ++k) {
        float wi0 = Wih[k * 192 + lane];
        float wi1 = Wih[k * 192 + 64 + lane];
        float wi2 = Wih[k * 192 + 128 + lane];
        float wh0 = Whh[k * 192 + lane];
        float wh1 = Whh[k * 192 + 64 + lane];
        float wh2 = Whh[k * 192 + 128 + lane];
#pragma unroll
        for (int q = 0; q < 4; ++q) {
            float mk = bcast(m[q], k), hk = bcast(fv[q], k);
            sr[q] = fmaf(mk, wi0, fmaf(hk, wh0, sr[q]));
            sz[q] = fmaf(mk, wi1, fmaf(hk, wh1, sz[q]));
            gn[q] = fmaf(mk, wi2, gn[q]);
            gh[q] = fmaf(hk, wh2, gh[q]);
        }
    }
#pragma unroll
    for (int q = 0; q < 4; ++q) {
        float rr = 1.f / (1.f + __expf(-sr[q]));
        float zz = 1.f / (1.f + __expf(-sz[q]));
        float ng = tanhf(gn[q] + rr * gh[q]);
        Fout[(size_t)(nq + q) * 64 + lane] = (1.f - zz) * ng + zz * fv[q];
    }
}

// ---------------- final ----------------
__global__ __launch_bounds__(256) void k_final(const float* __restrict__ F,
                                               const float* __restrict__ W1,
                                               const float* __restrict__ b1f,
                                               const float* __restrict__ W2l,
                                               const float* __restrict__ b2f,
                                               float* __restrict__ out) {
    int lane = threadIdx.x & 63, wv = threadIdx.x >> 6;
    int n = blockIdx.x * 4 + wv;
    float fv = F[n * 64 + lane];
    float acc = b1f[lane];
#pragma unroll
    for (int k = 0; k < 64; ++k) acc += bcast(fv, k) * W1[k * 64 + lane];
    acc = fmaxf(acc, 0.f);
    float p = acc * W2l[lane];
#pragma unroll
    for (int off = 32; off; off >>= 1) p += __shfl_xor(p, off, 64);
    if (lane == 0) out[n] = p + b2f[0];
}

extern "C" void kernel_launch(void* const* d_in, const int* in_sizes, int n_in,
                              void* d_out, int out_size, void* d_ws, size_t ws_size,
                              hipStream_t stream) {
    const float* x = (const float*)d_in[0];
    const int* ei = (const int*)d_in[1];
    const float* ea = (const float*)d_in[2];
    const float* l0w = (const float*)d_in[3];
    const float* l0b = (const float*)d_in[4];
    const float* n1w = (const float*)d_in[5];
    const float* n1b = (const float*)d_in[6];
    const float* n2w = (const float*)d_in[7];
    const float* n2b = (const float*)d_in[8];
    const float* cr = (const float*)d_in[9];
    const float* cb = (const float*)d_in[10];
    const float* wih = (const float*)d_in[11];
    const float* whh = (const float*)d_in[12];
    const float* bih = (const float*)d_in[13];
    const float* bhh = (const float*)d_in[14];
    const float* l1w = (const float*)d_in[15];
    const float* l1b = (const float*)d_in[16];
    const float* l2w = (const float*)d_in[17];
    const float* l2b = (const float*)d_in[18];

    char* w = (char*)d_ws;
    size_t off = 0;
    float* F0 = (float*)(w + off); off += (size_t)NN * 64 * 4;
    float* F1 = (float*)(w + off); off += (size_t)NN * 64 * 4;
    float* hE = (float*)(w + off); off += (size_t)NE * 64 * 4;
    ushort* W2FH = (ushort*)(w + off); off += (size_t)64 * 4096 * 2;
    ushort* W2FL = (ushort*)(w + off); off += (size_t)64 * 4096 * 2;
    ushort* GH = (ushort*)(w + off); off += (size_t)NP * 4096 * 2;    // 84 MB
    float* AggP = (float*)(w + off); off += (size_t)16 * NN * 64 * 4; // 41 MB
    float* Usb = (float*)(w + off); off += (size_t)NN * 64 * 4;       // 2.5 MB
    float* invd = (float*)(w + off); off += (size_t)NN * 4;
    int* deg = (int*)(w + off); off += (size_t)NN * 4;
    int* rowp = (int*)(w + off); off += (size_t)(NN + 1) * 4 + 252; off &= ~(size_t)255;
    int* fill = (int*)(w + off); off += (size_t)NN * 4;
    int* csrs = (int*)(w + off); off += (size_t)NE * 4;
    int* csre = (int*)(w + off); off += (size_t)NE * 4;

    hipMemsetAsync(deg, 0, NN * 4, stream);
    k_count<<<(NE + 255) / 256, 256, 0, stream>>>(ei, deg);
    k_scan<<<1, 1024, 0, stream>>>(deg, rowp, fill, invd);
    k_fill<<<(NE + 255) / 256, 256, 0, stream>>>(ei, fill, csrs, csre);
    k_w2f<<<1024, 256, 0, stream>>>(n2w, W2FH, W2FL);
    k_edge_h<<<NE / 4, 256, 0, stream>>>(ea, n1w, n1b, hE);
    k_lin0<<<NN / 4, 256, 0, stream>>>(x, l0w, l0b, F0);
    float* Fcur = F0;
    float* Fnxt = F1;
    for (int it = 0; it < 3; ++it) {
        k_gather<<<NN / 4, 256, 0, stream>>>(Fcur, hE, rowp, csrs, csre, GH, Usb);
        k_contract<<<512, 512, 0, stream>>>(GH, W2FH, W2FL, AggP);
        k_epi<<<NN / 16, 256, 0, stream>>>(AggP, Usb, n2b, invd, Fcur, cr, cb,
                                           wih, whh, bih, bhh, Fnxt);
        float* t = Fcur; Fcur = Fnxt; Fnxt = t;
    }
    k_final<<<NN / 4, 256, 0, stream>>>(Fcur, l1w, l1b, l2w, l2b, (float*)d_out);
}

// Round 22
// 309.765 us; speedup vs baseline: 1.0791x; 1.0791x over previous
//
#include <hip/hip_runtime.h>
#include <hip/hip_bf16.h>

#define NN 10000
#define NP 10240  // GHT rows padded: 32 m-chunks x 20 m-groups x 16 rows
#define NE 50000
#define FIN 40
#define FE 10
#define MCH 20    // m-groups per contract m-chunk
// L = 64

typedef float f32x4 __attribute__((ext_vector_type(4)));
typedef short s16x8 __attribute__((ext_vector_type(8)));

__device__ __forceinline__ float bcast(float v, int lane) {
    return __uint_as_float(__builtin_amdgcn_readlane(__float_as_uint(v), lane));
}
__device__ __forceinline__ int bcast_i(int v, int lane) {
    return __builtin_amdgcn_readlane(v, lane);
}
__device__ __forceinline__ ushort f2bf(float f) {
    uint u = __float_as_uint(f);
    uint r = (u + 0x7FFFu + ((u >> 16) & 1u)) >> 16;
    return (ushort)r;
}
__device__ __forceinline__ float bf2f(ushort h) {
    return __uint_as_float(((uint)h) << 16);
}

// ---------------- CSR build ----------------
__global__ void k_count(const int* __restrict__ ei, int* __restrict__ deg) {
    int e = blockIdx.x * 256 + threadIdx.x;
    if (e < NE) atomicAdd(&deg[ei[NE + e]], 1);
}

__global__ __launch_bounds__(1024) void k_scan(const int* __restrict__ deg,
                                               int* __restrict__ rowp,
                                               int* __restrict__ fill,
                                               float* __restrict__ invd) {
    __shared__ int wsum[16];
    __shared__ int chunkbase;
    int tid = threadIdx.x, lane = tid & 63, wv = tid >> 6;
    if (tid == 0) chunkbase = 0;
    __syncthreads();
    for (int base = 0; base < NN; base += 1024) {
        int idx = base + tid;
        int v = (idx < NN) ? deg[idx] : 0;
        int s = v;
#pragma unroll
        for (int off = 1; off < 64; off <<= 1) {
            int t = __shfl_up(s, off, 64);
            if (lane >= off) s += t;
        }
        if (lane == 63) wsum[wv] = s;
        __syncthreads();
        int carry = chunkbase;
        if (wv == 0 && lane < 16) {
            int x = wsum[lane];
#pragma unroll
            for (int off = 1; off < 16; off <<= 1) {
                int t = __shfl_up(x, off, 64);
                if (lane >= off) x += t;
            }
            wsum[lane] = x;  // inclusive over waves
        }
        __syncthreads();
        int wpre = (wv == 0) ? 0 : wsum[wv - 1];
        int incl = carry + wpre + s;
        if (idx < NN) {
            rowp[idx] = incl - v;
            fill[idx] = incl - v;
            invd[idx] = 1.0f / (float)(v > 0 ? v : 1);
        }
        __syncthreads();
        if (tid == 0) chunkbase = carry + wsum[15];
        __syncthreads();
    }
    if (tid == 0) rowp[NN] = NE;
}

__global__ void k_fill(const int* __restrict__ ei, int* __restrict__ fill,
                       int* __restrict__ csrs, int* __restrict__ csre) {
    int e = blockIdx.x * 256 + threadIdx.x;
    if (e < NE) {
        int d = ei[NE + e];
        int p = atomicAdd(&fill[d], 1);
        csrs[p] = ei[e];
        csre[p] = e;
    }
}

// ---------------- W2 split-bf16, transposed to [o][ki] (ki = k*64+i) ----------------
__global__ __launch_bounds__(256) void k_w2f(const float* __restrict__ n2w,
                                             ushort* __restrict__ W2FH,
                                             ushort* __restrict__ W2FL) {
    int lane = threadIdx.x & 63, wvl = threadIdx.x >> 6;
    int ki = blockIdx.x * 4 + wvl;
    float v = n2w[(size_t)ki * 64 + lane];
    ushort hi = f2bf(v);
    ushort lo = f2bf(v - bf2f(hi));
    W2FH[(size_t)lane * 4096 + ki] = hi;
    W2FL[(size_t)lane * 4096 + ki] = lo;
}

// ---------------- edge MLP: hE = relu(edge_attr @ nn1_w + nn1_b) ----------------
__global__ __launch_bounds__(256) void k_edge_h(const float* __restrict__ ea,
                                                const float* __restrict__ w1,
                                                const float* __restrict__ b1,
                                                float* __restrict__ hE) {
    int lane = threadIdx.x & 63, wv = threadIdx.x >> 6;
    int e = blockIdx.x * 4 + wv;
    float av = (lane < FE) ? ea[e * FE + lane] : 0.f;
    float acc = b1[lane];
#pragma unroll
    for (int j = 0; j < FE; ++j) acc += bcast(av, j) * w1[j * 64 + lane];
    hE[e * 64 + lane] = fmaxf(acc, 0.f);
}

// ---------------- lin0 ----------------
__global__ __launch_bounds__(256) void k_lin0(const float* __restrict__ x,
                                              const float* __restrict__ w0,
                                              const float* __restrict__ b0,
                                              float* __restrict__ F) {
    int lane = threadIdx.x & 63, wv = threadIdx.x >> 6;
    int n = blockIdx.x * 4 + wv;
    float xv = (lane < FIN) ? x[n * FIN + lane] : 0.f;
    float acc = b0[lane];
#pragma unroll
    for (int k = 0; k < FIN; ++k) acc += bcast(xv, k) * w0[k * 64 + lane];
    F[n * 64 + lane] = fmaxf(acc, 0.f);
}

// ---------------- gather (R19-best): tiled GHT + two-pass 16KB LDS transpose ----
// Tiled GHT[mg][kc][r][8] keeps contract's per-mg A-slice one contiguous 8KB
// stream (R20 A/B: flat layout cost ~25us total). Gather's 16B-stride stores
// are merged by L2 (WRITE_SIZE stays at logical 83MB). Gs halved to 16KB
// (residency cap 8 blocks/CU) via two k-half passes; 2-edge unroll.
__global__ __launch_bounds__(256) void k_gather(
    const float* __restrict__ F, const float* __restrict__ hE,
    const int* __restrict__ rowp, const int* __restrict__ csrs,
    const int* __restrict__ csre,
    ushort* __restrict__ GHT, float* __restrict__ Usb) {
    __shared__ __align__(16) ushort Gs[4][2048];  // 16 KB
    int tid = threadIdx.x, lane = tid & 63, wv = tid >> 6;
    int n = __builtin_amdgcn_readfirstlane(blockIdx.x * 4 + wv);
    int beg = __builtin_amdgcn_readfirstlane(rowp[n]);
    int end = __builtin_amdgcn_readfirstlane(rowp[n + 1]);

    float G[64];
#pragma unroll
    for (int k = 0; k < 64; ++k) G[k] = 0.f;
    float usum = 0.f;
    {
        int p0 = beg + lane;
        int sl = (p0 < end) ? csrs[p0] : 0;
        int el = (p0 < end) ? csre[p0] : 0;
        int nb = min(end - beg, 64);
        int j = 0;
        for (; j + 1 < nb; j += 2) {
            int s0 = bcast_i(sl, j), e0 = bcast_i(el, j);
            int s1 = bcast_i(sl, j + 1), e1 = bcast_i(el, j + 1);
            float u0 = F[(size_t)s0 * 64 + lane];
            float h0 = hE[(size_t)e0 * 64 + lane];
            float u1 = F[(size_t)s1 * 64 + lane];
            float h1 = hE[(size_t)e1 * 64 + lane];
            usum += u0;
            usum += u1;
#pragma unroll
            for (int k = 0; k < 64; ++k)
                G[k] = fmaf(bcast(h1, k), u1, fmaf(bcast(h0, k), u0, G[k]));
        }
        if (j < nb) {
            int s0 = bcast_i(sl, j), e0 = bcast_i(el, j);
            float u0 = F[(size_t)s0 * 64 + lane];
            float h0 = hE[(size_t)e0 * 64 + lane];
            usum += u0;
#pragma unroll
            for (int k = 0; k < 64; ++k) G[k] = fmaf(bcast(h0, k), u0, G[k]);
        }
        for (int p = beg + 64; p < end; ++p) {  // deg>64: rare
            int s = __builtin_amdgcn_readfirstlane(csrs[p]);
            int e = __builtin_amdgcn_readfirstlane(csre[p]);
            float u = F[(size_t)s * 64 + lane];
            float hv = hE[(size_t)e * 64 + lane];
            usum += u;
#pragma unroll
            for (int k = 0; k < 64; ++k) G[k] = fmaf(bcast(hv, k), u, G[k]);
        }
    }
    Usb[(size_t)n * 64 + lane] = usum;
    int r = n & 15;
    ushort* gout = GHT + (size_t)(n >> 4) * 65536 + r * 8;
    // pass 0: k in [0,32) -> global kc in [0,256)
#pragma unroll
    for (int k = 0; k < 32; ++k) Gs[wv][k * 64 + lane] = f2bf(G[k]);
    __syncthreads();
#pragma unroll
    for (int it = 0; it < 4; ++it) {
        int kc = it * 64 + lane;
        *(s16x8*)&gout[(size_t)kc * 128] = *(const s16x8*)&Gs[wv][kc * 8];
    }
    __syncthreads();
    // pass 1: k in [32,64) -> global kc in [256,512)
#pragma unroll
    for (int k = 0; k < 32; ++k) Gs[wv][k * 64 + lane] = f2bf(G[32 + k]);
    __syncthreads();
#pragma unroll
    for (int it = 0; it < 4; ++it) {
        int kc = it * 64 + lane;
        *(s16x8*)&gout[(size_t)(256 + kc) * 128] = *(const s16x8*)&Gs[wv][kc * 8];
    }
}

// ---------------- contract v7 (R15/R19 verbatim): B-stationary + tiled-A ----------------
__global__ __launch_bounds__(512) void k_contract(
    const ushort* __restrict__ GHT, const ushort* __restrict__ W2FH,
    const ushort* __restrict__ W2FL, float* __restrict__ AggP) {
    __shared__ __align__(16) ushort BH[64 * 264];  // 33792 B
    __shared__ __align__(16) ushort BL[64 * 264];  // 33792 B
    int tid = threadIdx.x, lane = tid & 63, wv = tid >> 6;
    int ks = blockIdx.x & 15;  // ki sixteenth
    int mc = blockIdx.x >> 4;  // 0..31
    int kbase = ks * 256;
    int otile = wv & 3, mhalf = wv >> 2;
    int arow = lane & 15, agrp = lane >> 4;
    int o = otile * 16 + arow;

#pragma unroll
    for (int rep = 0; rep < 4; ++rep) {
        int off = rep * 4096 + tid * 8;
        int row = off >> 8, col = off & 255;
        *(s16x8*)&BH[row * 264 + col] =
            *(const s16x8*)&W2FH[(size_t)row * 4096 + kbase + col];
        *(s16x8*)&BL[row * 264 + col] =
            *(const s16x8*)&W2FL[(size_t)row * 4096 + kbase + col];
    }
    __syncthreads();

    int mg0 = mc * MCH;
    int mgend = mg0 + MCH;
    float* ap = AggP + (size_t)ks * NN * 64;
    for (int mg = mg0 + mhalf * 2; mg < mgend; mg += 4) {
        // A slice for (mg, ks): contiguous 8KB at GHT + mg*65536 + ks*4096
        const ushort* pA = GHT + (size_t)mg * 65536 + (size_t)ks * 4096 + arow * 8;
        const ushort* pB = pA + 65536;
        f32x4 a0h = {0.f, 0.f, 0.f, 0.f};
        f32x4 a0l = {0.f, 0.f, 0.f, 0.f};
        f32x4 a1h = {0.f, 0.f, 0.f, 0.f};
        f32x4 a1l = {0.f, 0.f, 0.f, 0.f};
#pragma unroll 4
        for (int s = 0; s < 8; ++s) {
            int aoff = (s * 4 + agrp) * 128;  // kc*128; lanes contiguous by arow
            int kil = s * 32 + agrp * 8;
            s16x8 a0 = *(const s16x8*)&pA[aoff];
            s16x8 a1 = *(const s16x8*)&pB[aoff];
            s16x8 bh = *(const s16x8*)&BH[o * 264 + kil];
            s16x8 bl = *(const s16x8*)&BL[o * 264 + kil];
            a0h = __builtin_amdgcn_mfma_f32_16x16x32_bf16(a0, bh, a0h, 0, 0, 0);
            a1h = __builtin_amdgcn_mfma_f32_16x16x32_bf16(a1, bh, a1h, 0, 0, 0);
            a0l = __builtin_amdgcn_mfma_f32_16x16x32_bf16(a0, bl, a0l, 0, 0, 0);
            a1l = __builtin_amdgcn_mfma_f32_16x16x32_bf16(a1, bl, a1l, 0, 0, 0);
        }
        f32x4 acc0 = a0h + a0l;
        f32x4 acc1 = a1h + a1l;
        // D row r -> node mg*16 + agrp*4 + r
#pragma unroll
        for (int r = 0; r < 4; ++r) {
            int n0r = mg * 16 + agrp * 4 + r;
            if (n0r < NN) ap[(size_t)n0r * 64 + o] = acc0[r];
            int n1r = (mg + 1) * 16 + agrp * 4 + r;
            if (n1r < NN) ap[(size_t)n1r * 64 + o] = acc1[r];
        }
    }
}

// ---------------- epilogue (R15 verbatim) ----------------
__global__ __launch_bounds__(256) void k_epi(
    const float* __restrict__ AggP, const float* __restrict__ Usb,
    const float* __restrict__ B2, const float* __restrict__ invd,
    const float* __restrict__ F, const float* __restrict__ Wroot,
    const float* __restrict__ broot, const float* __restrict__ Wih,
    const float* __restrict__ Whh, const float* __restrict__ bih,
    const float* __restrict__ bhh, float* __restrict__ Fout) {
    int lane = threadIdx.x & 63, wv = threadIdx.x >> 6;
    int nq = blockIdx.x * 16 + wv * 4;

    float fv[4], uv[4], aa[4], rt[4], bt[4];
#pragma unroll
    for (int q = 0; q < 4; ++q) {
        size_t idx = (size_t)(nq + q) * 64 + lane;
        fv[q] = F[idx];
        uv[q] = Usb[idx];
        float s = 0.f;
#pragma unroll
        for (int ks = 0; ks < 16; ++ks) s += AggP[(size_t)ks * NN * 64 + idx];
        aa[q] = s;
        rt[q] = broot[lane];
        bt[q] = 0.f;
    }
#pragma unroll 8
    for (int k = 0; k < 64; ++k) {
        float wr = Wroot[k * 64 + lane];
        float b2 = B2[k * 64 + lane];
#pragma unroll
        for (int q = 0; q < 4; ++q) {
            rt[q] = fmaf(bcast(fv[q], k), wr, rt[q]);
            bt[q] = fmaf(bcast(uv[q], k), b2, bt[q]);
        }
    }
    float m[4];
#pragma unroll
    for (int q = 0; q < 4; ++q)
        m[q] = fmaxf((aa[q] + bt[q]) * invd[nq + q] + rt[q], 0.f);

    float sr[4], sz[4], gn[4], gh[4];
#pragma unroll
    for (int q = 0; q < 4; ++q) {
        sr[q] = bih[lane] + bhh[lane];
        sz[q] = bih[64 + lane] + bhh[64 + lane];
        gn[q] = bih[128 + lane];
        gh[q] = bhh[128 + lane];
    }
#pragma unroll 8
    for (int k = 0; k < 64; ++k) {
        float wi0 = Wih[k * 192 + lane];
        float wi1 = Wih[k * 192 + 64 + lane];
        float wi2 = Wih[k * 192 + 128 + lane];
        float wh0 = Whh[k * 192 + lane];
        float wh1 = Whh[k * 192 + 64 + lane];
        float wh2 = Whh[k * 192 + 128 + lane];
#pragma unroll
        for (int q = 0; q < 4; ++q) {
            float mk = bcast(m[q], k), hk = bcast(fv[q], k);
            sr[q] = fmaf(mk, wi0, fmaf(hk, wh0, sr[q]));
            sz[q] = fmaf(mk, wi1, fmaf(hk, wh1, sz[q]));
            gn[q] = fmaf(mk, wi2, gn[q]);
            gh[q] = fmaf(hk, wh2, gh[q]);
        }
    }
#pragma unroll
    for (int q = 0; q < 4; ++q) {
        float rr = 1.f / (1.f + __expf(-sr[q]));
        float zz = 1.f / (1.f + __expf(-sz[q]));
        float ng = tanhf(gn[q] + rr * gh[q]);
        Fout[(size_t)(nq + q) * 64 + lane] = (1.f - zz) * ng + zz * fv[q];
    }
}

// ---------------- final ----------------
__global__ __launch_bounds__(256) void k_final(const float* __restrict__ F,
                                               const float* __restrict__ W1,
                                               const float* __restrict__ b1f,
                                               const float* __restrict__ W2l,
                                               const float* __restrict__ b2f,
                                               float* __restrict__ out) {
    int lane = threadIdx.x & 63, wv = threadIdx.x >> 6;
    int n = blockIdx.x * 4 + wv;
    float fv = F[n * 64 + lane];
    float acc = b1f[lane];
#pragma unroll
    for (int k = 0; k < 64; ++k) acc += bcast(fv, k) * W1[k * 64 + lane];
    acc = fmaxf(acc, 0.f);
    float p = acc * W2l[lane];
#pragma unroll
    for (int off = 32; off; off >>= 1) p += __shfl_xor(p, off, 64);
    if (lane == 0) out[n] = p + b2f[0];
}

extern "C" void kernel_launch(void* const* d_in, const int* in_sizes, int n_in,
                              void* d_out, int out_size, void* d_ws, size_t ws_size,
                              hipStream_t stream) {
    const float* x = (const float*)d_in[0];
    const int* ei = (const int*)d_in[1];
    const float* ea = (const float*)d_in[2];
    const float* l0w = (const float*)d_in[3];
    const float* l0b = (const float*)d_in[4];
    const float* n1w = (const float*)d_in[5];
    const float* n1b = (const float*)d_in[6];
    const float* n2w = (const float*)d_in[7];
    const float* n2b = (const float*)d_in[8];
    const float* cr = (const float*)d_in[9];
    const float* cb = (const float*)d_in[10];
    const float* wih = (const float*)d_in[11];
    const float* whh = (const float*)d_in[12];
    const float* bih = (const float*)d_in[13];
    const float* bhh = (const float*)d_in[14];
    const float* l1w = (const float*)d_in[15];
    const float* l1b = (const float*)d_in[16];
    const float* l2w = (const float*)d_in[17];
    const float* l2b = (const float*)d_in[18];

    char* w = (char*)d_ws;
    size_t off = 0;
    float* F0 = (float*)(w + off); off += (size_t)NN * 64 * 4;
    float* F1 = (float*)(w + off); off += (size_t)NN * 64 * 4;
    float* hE = (float*)(w + off); off += (size_t)NE * 64 * 4;
    ushort* W2FH = (ushort*)(w + off); off += (size_t)64 * 4096 * 2;
    ushort* W2FL = (ushort*)(w + off); off += (size_t)64 * 4096 * 2;
    ushort* GHT = (ushort*)(w + off); off += (size_t)NP * 4096 * 2;   // 84 MB
    float* AggP = (float*)(w + off); off += (size_t)16 * NN * 64 * 4; // 41 MB
    float* Usb = (float*)(w + off); off += (size_t)NN * 64 * 4;       // 2.5 MB
    float* invd = (float*)(w + off); off += (size_t)NN * 4;
    int* deg = (int*)(w + off); off += (size_t)NN * 4;
    int* rowp = (int*)(w + off); off += (size_t)(NN + 1) * 4 + 252; off &= ~(size_t)255;
    int* fill = (int*)(w + off); off += (size_t)NN * 4;
    int* csrs = (int*)(w + off); off += (size_t)NE * 4;
    int* csre = (int*)(w + off); off += (size_t)NE * 4;

    hipMemsetAsync(deg, 0, NN * 4, stream);
    k_count<<<(NE + 255) / 256, 256, 0, stream>>>(ei, deg);
    k_scan<<<1, 1024, 0, stream>>>(deg, rowp, fill, invd);
    k_fill<<<(NE + 255) / 256, 256, 0, stream>>>(ei, fill, csrs, csre);
    k_w2f<<<1024, 256, 0, stream>>>(n2w, W2FH, W2FL);
    k_edge_h<<<NE / 4, 256, 0, stream>>>(ea, n1w, n1b, hE);
    k_lin0<<<NN / 4, 256, 0, stream>>>(x, l0w, l0b, F0);
    float* Fcur = F0;
    float* Fnxt = F1;
    for (int it = 0; it < 3; ++it) {
        k_gather<<<NN / 4, 256, 0, stream>>>(Fcur, hE, rowp, csrs, csre, GHT, Usb);
        k_contract<<<512, 512, 0, stream>>>(GHT, W2FH, W2FL, AggP);
        k_epi<<<NN / 16, 256, 0, stream>>>(AggP, Usb, n2b, invd, Fcur, cr, cb,
                                           wih, whh, bih, bhh, Fnxt);
        float* t = Fcur; Fcur = Fnxt; Fnxt = t;
    }
    k_final<<<NN / 4, 256, 0, stream>>>(Fcur, l1w, l1b, l2w, l2b, (float*)d_out);
}

// Round 23
// 296.647 us; speedup vs baseline: 1.1269x; 1.0442x over previous
//
#include <hip/hip_runtime.h>
#include <hip/hip_bf16.h>

#define NN 10000
#define NP 10240  // GHT rows padded: 32 m-chunks x 20 m-groups x 16 rows
#define NE 50000
#define FIN 40
#define FE 10
#define MCH 20    // m-groups per contract m-chunk
// L = 64

typedef float f32x4 __attribute__((ext_vector_type(4)));
typedef short s16x8 __attribute__((ext_vector_type(8)));

__device__ __forceinline__ float bcast(float v, int lane) {
    return __uint_as_float(__builtin_amdgcn_readlane(__float_as_uint(v), lane));
}
__device__ __forceinline__ int bcast_i(int v, int lane) {
    return __builtin_amdgcn_readlane(v, lane);
}
__device__ __forceinline__ ushort f2bf(float f) {
    uint u = __float_as_uint(f);
    uint r = (u + 0x7FFFu + ((u >> 16) & 1u)) >> 16;
    return (ushort)r;
}
__device__ __forceinline__ float bf2f(ushort h) {
    return __uint_as_float(((uint)h) << 16);
}

// ---------------- CSR build ----------------
__global__ void k_count(const int* __restrict__ ei, int* __restrict__ deg) {
    int e = blockIdx.x * 256 + threadIdx.x;
    if (e < NE) atomicAdd(&deg[ei[NE + e]], 1);
}

__global__ __launch_bounds__(1024) void k_scan(const int* __restrict__ deg,
                                               int* __restrict__ rowp,
                                               int* __restrict__ fill,
                                               float* __restrict__ invd) {
    __shared__ int wsum[16];
    __shared__ int chunkbase;
    int tid = threadIdx.x, lane = tid & 63, wv = tid >> 6;
    if (tid == 0) chunkbase = 0;
    __syncthreads();
    for (int base = 0; base < NN; base += 1024) {
        int idx = base + tid;
        int v = (idx < NN) ? deg[idx] : 0;
        int s = v;
#pragma unroll
        for (int off = 1; off < 64; off <<= 1) {
            int t = __shfl_up(s, off, 64);
            if (lane >= off) s += t;
        }
        if (lane == 63) wsum[wv] = s;
        __syncthreads();
        int carry = chunkbase;
        if (wv == 0 && lane < 16) {
            int x = wsum[lane];
#pragma unroll
            for (int off = 1; off < 16; off <<= 1) {
                int t = __shfl_up(x, off, 64);
                if (lane >= off) x += t;
            }
            wsum[lane] = x;  // inclusive over waves
        }
        __syncthreads();
        int wpre = (wv == 0) ? 0 : wsum[wv - 1];
        int incl = carry + wpre + s;
        if (idx < NN) {
            rowp[idx] = incl - v;
            fill[idx] = incl - v;
            invd[idx] = 1.0f / (float)(v > 0 ? v : 1);
        }
        __syncthreads();
        if (tid == 0) chunkbase = carry + wsum[15];
        __syncthreads();
    }
    if (tid == 0) rowp[NN] = NE;
}

__global__ void k_fill(const int* __restrict__ ei, int* __restrict__ fill,
                       int* __restrict__ csrs, int* __restrict__ csre) {
    int e = blockIdx.x * 256 + threadIdx.x;
    if (e < NE) {
        int d = ei[NE + e];
        int p = atomicAdd(&fill[d], 1);
        csrs[p] = ei[e];
        csre[p] = e;
    }
}

// ---------------- W2 split-bf16, transposed to [o][ki] (ki = k*64+i) ----------------
__global__ __launch_bounds__(256) void k_w2f(const float* __restrict__ n2w,
                                             ushort* __restrict__ W2FH,
                                             ushort* __restrict__ W2FL) {
    int lane = threadIdx.x & 63, wvl = threadIdx.x >> 6;
    int ki = blockIdx.x * 4 + wvl;
    float v = n2w[(size_t)ki * 64 + lane];
    ushort hi = f2bf(v);
    ushort lo = f2bf(v - bf2f(hi));
    W2FH[(size_t)lane * 4096 + ki] = hi;
    W2FL[(size_t)lane * 4096 + ki] = lo;
}

// ---------------- edge MLP: hE = relu(edge_attr @ nn1_w + nn1_b) ----------------
__global__ __launch_bounds__(256) void k_edge_h(const float* __restrict__ ea,
                                                const float* __restrict__ w1,
                                                const float* __restrict__ b1,
                                                float* __restrict__ hE) {
    int lane = threadIdx.x & 63, wv = threadIdx.x >> 6;
    int e = blockIdx.x * 4 + wv;
    float av = (lane < FE) ? ea[e * FE + lane] : 0.f;
    float acc = b1[lane];
#pragma unroll
    for (int j = 0; j < FE; ++j) acc += bcast(av, j) * w1[j * 64 + lane];
    hE[e * 64 + lane] = fmaxf(acc, 0.f);
}

// ---------------- lin0 ----------------
__global__ __launch_bounds__(256) void k_lin0(const float* __restrict__ x,
                                              const float* __restrict__ w0,
                                              const float* __restrict__ b0,
                                              float* __restrict__ F) {
    int lane = threadIdx.x & 63, wv = threadIdx.x >> 6;
    int n = blockIdx.x * 4 + wv;
    float xv = (lane < FIN) ? x[n * FIN + lane] : 0.f;
    float acc = b0[lane];
#pragma unroll
    for (int k = 0; k < FIN; ++k) acc += bcast(xv, k) * w0[k * 64 + lane];
    F[n * 64 + lane] = fmaxf(acc, 0.f);
}

// ---------------- gather (R19-best): tiled GHT + two-pass 16KB LDS transpose ----
__global__ __launch_bounds__(256) void k_gather(
    const float* __restrict__ F, const float* __restrict__ hE,
    const int* __restrict__ rowp, const int* __restrict__ csrs,
    const int* __restrict__ csre,
    ushort* __restrict__ GHT, float* __restrict__ Usb) {
    __shared__ __align__(16) ushort Gs[4][2048];  // 16 KB
    int tid = threadIdx.x, lane = tid & 63, wv = tid >> 6;
    int n = __builtin_amdgcn_readfirstlane(blockIdx.x * 4 + wv);
    int beg = __builtin_amdgcn_readfirstlane(rowp[n]);
    int end = __builtin_amdgcn_readfirstlane(rowp[n + 1]);

    float G[64];
#pragma unroll
    for (int k = 0; k < 64; ++k) G[k] = 0.f;
    float usum = 0.f;
    {
        int p0 = beg + lane;
        int sl = (p0 < end) ? csrs[p0] : 0;
        int el = (p0 < end) ? csre[p0] : 0;
        int nb = min(end - beg, 64);
        int j = 0;
        for (; j + 1 < nb; j += 2) {
            int s0 = bcast_i(sl, j), e0 = bcast_i(el, j);
            int s1 = bcast_i(sl, j + 1), e1 = bcast_i(el, j + 1);
            float u0 = F[(size_t)s0 * 64 + lane];
            float h0 = hE[(size_t)e0 * 64 + lane];
            float u1 = F[(size_t)s1 * 64 + lane];
            float h1 = hE[(size_t)e1 * 64 + lane];
            usum += u0;
            usum += u1;
#pragma unroll
            for (int k = 0; k < 64; ++k)
                G[k] = fmaf(bcast(h1, k), u1, fmaf(bcast(h0, k), u0, G[k]));
        }
        if (j < nb) {
            int s0 = bcast_i(sl, j), e0 = bcast_i(el, j);
            float u0 = F[(size_t)s0 * 64 + lane];
            float h0 = hE[(size_t)e0 * 64 + lane];
            usum += u0;
#pragma unroll
            for (int k = 0; k < 64; ++k) G[k] = fmaf(bcast(h0, k), u0, G[k]);
        }
        for (int p = beg + 64; p < end; ++p) {  // deg>64: rare
            int s = __builtin_amdgcn_readfirstlane(csrs[p]);
            int e = __builtin_amdgcn_readfirstlane(csre[p]);
            float u = F[(size_t)s * 64 + lane];
            float hv = hE[(size_t)e * 64 + lane];
            usum += u;
#pragma unroll
            for (int k = 0; k < 64; ++k) G[k] = fmaf(bcast(hv, k), u, G[k]);
        }
    }
    Usb[(size_t)n * 64 + lane] = usum;
    int r = n & 15;
    ushort* gout = GHT + (size_t)(n >> 4) * 65536 + r * 8;
    // pass 0: k in [0,32) -> global kc in [0,256)
#pragma unroll
    for (int k = 0; k < 32; ++k) Gs[wv][k * 64 + lane] = f2bf(G[k]);
    __syncthreads();
#pragma unroll
    for (int it = 0; it < 4; ++it) {
        int kc = it * 64 + lane;
        *(s16x8*)&gout[(size_t)kc * 128] = *(const s16x8*)&Gs[wv][kc * 8];
    }
    __syncthreads();
    // pass 1: k in [32,64) -> global kc in [256,512)
#pragma unroll
    for (int k = 0; k < 32; ++k) Gs[wv][k * 64 + lane] = f2bf(G[32 + k]);
    __syncthreads();
#pragma unroll
    for (int it = 0; it < 4; ++it) {
        int kc = it * 64 + lane;
        *(s16x8*)&gout[(size_t)(256 + kc) * 128] = *(const s16x8*)&Gs[wv][kc * 8];
    }
}

// ---------------- contract v7b: B-stationary + tiled-A, bf16 partials ----------------
// AggP stored bf16: halves partial-sum round-trip traffic (41->20.5 MB write
// here, same on epi's read). Fixed order, deterministic; added quantization
// ~0.4% of partial magnitude, bounded by existing bf16-G error budget.
__global__ __launch_bounds__(512) void k_contract(
    const ushort* __restrict__ GHT, const ushort* __restrict__ W2FH,
    const ushort* __restrict__ W2FL, ushort* __restrict__ AggPH) {
    __shared__ __align__(16) ushort BH[64 * 264];  // 33792 B
    __shared__ __align__(16) ushort BL[64 * 264];  // 33792 B
    int tid = threadIdx.x, lane = tid & 63, wv = tid >> 6;
    int ks = blockIdx.x & 15;  // ki sixteenth
    int mc = blockIdx.x >> 4;  // 0..31
    int kbase = ks * 256;
    int otile = wv & 3, mhalf = wv >> 2;
    int arow = lane & 15, agrp = lane >> 4;
    int o = otile * 16 + arow;

#pragma unroll
    for (int rep = 0; rep < 4; ++rep) {
        int off = rep * 4096 + tid * 8;
        int row = off >> 8, col = off & 255;
        *(s16x8*)&BH[row * 264 + col] =
            *(const s16x8*)&W2FH[(size_t)row * 4096 + kbase + col];
        *(s16x8*)&BL[row * 264 + col] =
            *(const s16x8*)&W2FL[(size_t)row * 4096 + kbase + col];
    }
    __syncthreads();

    int mg0 = mc * MCH;
    int mgend = mg0 + MCH;
    ushort* ap = AggPH + (size_t)ks * NN * 64;
    for (int mg = mg0 + mhalf * 2; mg < mgend; mg += 4) {
        // A slice for (mg, ks): contiguous 8KB at GHT + mg*65536 + ks*4096
        const ushort* pA = GHT + (size_t)mg * 65536 + (size_t)ks * 4096 + arow * 8;
        const ushort* pB = pA + 65536;
        f32x4 a0h = {0.f, 0.f, 0.f, 0.f};
        f32x4 a0l = {0.f, 0.f, 0.f, 0.f};
        f32x4 a1h = {0.f, 0.f, 0.f, 0.f};
        f32x4 a1l = {0.f, 0.f, 0.f, 0.f};
#pragma unroll 4
        for (int s = 0; s < 8; ++s) {
            int aoff = (s * 4 + agrp) * 128;  // kc*128; lanes contiguous by arow
            int kil = s * 32 + agrp * 8;
            s16x8 a0 = *(const s16x8*)&pA[aoff];
            s16x8 a1 = *(const s16x8*)&pB[aoff];
            s16x8 bh = *(const s16x8*)&BH[o * 264 + kil];
            s16x8 bl = *(const s16x8*)&BL[o * 264 + kil];
            a0h = __builtin_amdgcn_mfma_f32_16x16x32_bf16(a0, bh, a0h, 0, 0, 0);
            a1h = __builtin_amdgcn_mfma_f32_16x16x32_bf16(a1, bh, a1h, 0, 0, 0);
            a0l = __builtin_amdgcn_mfma_f32_16x16x32_bf16(a0, bl, a0l, 0, 0, 0);
            a1l = __builtin_amdgcn_mfma_f32_16x16x32_bf16(a1, bl, a1l, 0, 0, 0);
        }
        f32x4 acc0 = a0h + a0l;
        f32x4 acc1 = a1h + a1l;
        // D row r -> node mg*16 + agrp*4 + r
#pragma unroll
        for (int r = 0; r < 4; ++r) {
            int n0r = mg * 16 + agrp * 4 + r;
            if (n0r < NN) ap[(size_t)n0r * 64 + o] = f2bf(acc0[r]);
            int n1r = (mg + 1) * 16 + agrp * 4 + r;
            if (n1r < NN) ap[(size_t)n1r * 64 + o] = f2bf(acc1[r]);
        }
    }
}

// ---------------- epilogue: sum 16 bf16 partials + mean + nn2_b + root + GRU ----------------
__global__ __launch_bounds__(256) void k_epi(
    const ushort* __restrict__ AggPH, const float* __restrict__ Usb,
    const float* __restrict__ B2, const float* __restrict__ invd,
    const float* __restrict__ F, const float* __restrict__ Wroot,
    const float* __restrict__ broot, const float* __restrict__ Wih,
    const float* __restrict__ Whh, const float* __restrict__ bih,
    const float* __restrict__ bhh, float* __restrict__ Fout) {
    int lane = threadIdx.x & 63, wv = threadIdx.x >> 6;
    int nq = blockIdx.x * 16 + wv * 4;

    float fv[4], uv[4], aa[4], rt[4], bt[4];
#pragma unroll
    for (int q = 0; q < 4; ++q) {
        size_t idx = (size_t)(nq + q) * 64 + lane;
        fv[q] = F[idx];
        uv[q] = Usb[idx];
        float s = 0.f;
#pragma unroll
        for (int ks = 0; ks < 16; ++ks)
            s += bf2f(AggPH[(size_t)ks * NN * 64 + idx]);
        aa[q] = s;
        rt[q] = broot[lane];
        bt[q] = 0.f;
    }
#pragma unroll 8
    for (int k = 0; k < 64; ++k) {
        float wr = Wroot[k * 64 + lane];
        float b2 = B2[k * 64 + lane];
#pragma unroll
        for (int q = 0; q < 4; ++q) {
            rt[q] = fmaf(bcast(fv[q], k), wr, rt[q]);
            bt[q] = fmaf(bcast(uv[q], k), b2, bt[q]);
        }
    }
    float m[4];
#pragma unroll
    for (int q = 0; q < 4; ++q)
        m[q] = fmaxf((aa[q] + bt[q]) * invd[nq + q] + rt[q], 0.f);

    float sr[4], sz[4], gn[4], gh[4];
#pragma unroll
    for (int q = 0; q < 4; ++q) {
        sr[q] = bih[lane] + bhh[lane];
        sz[q] = bih[64 + lane] + bhh[64 + lane];
        gn[q] = bih[128 + lane];
        gh[q] = bhh[128 + lane];
    }
#pragma unroll 8
    for (int k = 0; k < 64; ++k) {
        float wi0 = Wih[k * 192 + lane];
        float wi1 = Wih[k * 192 + 64 + lane];
        float wi2 = Wih[k * 192 + 128 + lane];
        float wh0 = Whh[k * 192 + lane];
        float wh1 = Whh[k * 192 + 64 + lane];
        float wh2 = Whh[k * 192 + 128 + lane];
#pragma unroll
        for (int q = 0; q < 4; ++q) {
            float mk = bcast(m[q], k), hk = bcast(fv[q], k);
            sr[q] = fmaf(mk, wi0, fmaf(hk, wh0, sr[q]));
            sz[q] = fmaf(mk, wi1, fmaf(hk, wh1, sz[q]));
            gn[q] = fmaf(mk, wi2, gn[q]);
            gh[q] = fmaf(hk, wh2, gh[q]);
        }
    }
#pragma unroll
    for (int q = 0; q < 4; ++q) {
        float rr = 1.f / (1.f + __expf(-sr[q]));
        float zz = 1.f / (1.f + __expf(-sz[q]));
        float ng = tanhf(gn[q] + rr * gh[q]);
        Fout[(size_t)(nq + q) * 64 + lane] = (1.f - zz) * ng + zz * fv[q];
    }
}

// ---------------- final ----------------
__global__ __launch_bounds__(256) void k_final(const float* __restrict__ F,
                                               const float* __restrict__ W1,
                                               const float* __restrict__ b1f,
                                               const float* __restrict__ W2l,
                                               const float* __restrict__ b2f,
                                               float* __restrict__ out) {
    int lane = threadIdx.x & 63, wv = threadIdx.x >> 6;
    int n = blockIdx.x * 4 + wv;
    float fv = F[n * 64 + lane];
    float acc = b1f[lane];
#pragma unroll
    for (int k = 0; k < 64; ++k) acc += bcast(fv, k) * W1[k * 64 + lane];
    acc = fmaxf(acc, 0.f);
    float p = acc * W2l[lane];
#pragma unroll
    for (int off = 32; off; off >>= 1) p += __shfl_xor(p, off, 64);
    if (lane == 0) out[n] = p + b2f[0];
}

extern "C" void kernel_launch(void* const* d_in, const int* in_sizes, int n_in,
                              void* d_out, int out_size, void* d_ws, size_t ws_size,
                              hipStream_t stream) {
    const float* x = (const float*)d_in[0];
    const int* ei = (const int*)d_in[1];
    const float* ea = (const float*)d_in[2];
    const float* l0w = (const float*)d_in[3];
    const float* l0b = (const float*)d_in[4];
    const float* n1w = (const float*)d_in[5];
    const float* n1b = (const float*)d_in[6];
    const float* n2w = (const float*)d_in[7];
    const float* n2b = (const float*)d_in[8];
    const float* cr = (const float*)d_in[9];
    const float* cb = (const float*)d_in[10];
    const float* wih = (const float*)d_in[11];
    const float* whh = (const float*)d_in[12];
    const float* bih = (const float*)d_in[13];
    const float* bhh = (const float*)d_in[14];
    const float* l1w = (const float*)d_in[15];
    const float* l1b = (const float*)d_in[16];
    const float* l2w = (const float*)d_in[17];
    const float* l2b = (const float*)d_in[18];

    char* w = (char*)d_ws;
    size_t off = 0;
    float* F0 = (float*)(w + off); off += (size_t)NN * 64 * 4;
    float* F1 = (float*)(w + off); off += (size_t)NN * 64 * 4;
    float* hE = (float*)(w + off); off += (size_t)NE * 64 * 4;
    ushort* W2FH = (ushort*)(w + off); off += (size_t)64 * 4096 * 2;
    ushort* W2FL = (ushort*)(w + off); off += (size_t)64 * 4096 * 2;
    ushort* GHT = (ushort*)(w + off); off += (size_t)NP * 4096 * 2;    // 84 MB
    ushort* AggPH = (ushort*)(w + off); off += (size_t)16 * NN * 64 * 2; // 20.5 MB
    float* Usb = (float*)(w + off); off += (size_t)NN * 64 * 4;        // 2.5 MB
    float* invd = (float*)(w + off); off += (size_t)NN * 4;
    int* deg = (int*)(w + off); off += (size_t)NN * 4;
    int* rowp = (int*)(w + off); off += (size_t)(NN + 1) * 4 + 252; off &= ~(size_t)255;
    int* fill = (int*)(w + off); off += (size_t)NN * 4;
    int* csrs = (int*)(w + off); off += (size_t)NE * 4;
    int* csre = (int*)(w + off); off += (size_t)NE * 4;

    hipMemsetAsync(deg, 0, NN * 4, stream);
    k_count<<<(NE + 255) / 256, 256, 0, stream>>>(ei, deg);
    k_scan<<<1, 1024, 0, stream>>>(deg, rowp, fill, invd);
    k_fill<<<(NE + 255) / 256, 256, 0, stream>>>(ei, fill, csrs, csre);
    k_w2f<<<1024, 256, 0, stream>>>(n2w, W2FH, W2FL);
    k_edge_h<<<NE / 4, 256, 0, stream>>>(ea, n1w, n1b, hE);
    k_lin0<<<NN / 4, 256, 0, stream>>>(x, l0w, l0b, F0);
    float* Fcur = F0;
    float* Fnxt = F1;
    for (int it = 0; it < 3; ++it) {
        k_gather<<<NN / 4, 256, 0, stream>>>(Fcur, hE, rowp, csrs, csre, GHT, Usb);
        k_contract<<<512, 512, 0, stream>>>(GHT, W2FH, W2FL, AggPH);
        k_epi<<<NN / 16, 256, 0, stream>>>(AggPH, Usb, n2b, invd, Fcur, cr, cb,
                                           wih, whh, bih, bhh, Fnxt);
        float* t = Fcur; Fcur = Fnxt; Fnxt = t;
    }
    k_final<<<NN / 4, 256, 0, stream>>>(Fcur, l1w, l1b, l2w, l2b, (float*)d_out);
}